// Round 2
// baseline (1656.110 us; speedup 1.0000x reference)
//
#include <hip/hip_runtime.h>
#include <hip/hip_bf16.h>

typedef unsigned short u16;
typedef __attribute__((ext_vector_type(8))) short short8;
typedef __attribute__((ext_vector_type(4))) float f32x4;

#define B_ 2
#define S_ 2048
#define E_ 2048
#define HQ_ 16
#define HKV_ 4
#define D_ 128
#define WINDOW_ 512

static __device__ __forceinline__ float bf2f(u16 u) {
    union { unsigned int i; float f; } v; v.i = ((unsigned int)u) << 16; return v.f;
}
static __device__ __forceinline__ u16 f2bf(float f) {
    unsigned int x = __float_as_uint(f);
    unsigned int r = (x + 0x7fffu + ((x >> 16) & 1u)) >> 16;
    return (u16)r;
}

// ---------------------------------------------------------------------------
// Dtype detector: reads Wq raw u16s. bf16 weights ~N(0,0.02) have bf16
// exponent <= ~0x7B; fp32 data read as u16 halfwords has ~45% exponent>=0x90.
// flag=1 -> inputs are fp32; flag=0 -> inputs are bf16.
// ---------------------------------------------------------------------------
__global__ void detect_kernel(const u16* __restrict__ Wq, int* __restrict__ flag)
{
    __shared__ int cnt;
    if (threadIdx.x == 0) cnt = 0;
    __syncthreads();
    int c = 0;
    #pragma unroll
    for (int k = 0; k < 16; ++k) {
        u16 v = Wq[threadIdx.x * 16 + k];
        int e = (v >> 7) & 0xFF;
        if (e >= 0x90) c++;
    }
    atomicAdd(&cnt, c);
    __syncthreads();
    if (threadIdx.x == 0) *flag = (cnt >= 256) ? 1 : 0;
}

// ---------------------------------------------------------------------------
// Converter: canonical bf16 copies of all inputs, concatenated in C.
// ---------------------------------------------------------------------------
#define NX   8388608u
#define OFF1 8388608u     // Wq
#define OFF2 12582912u    // bq
#define OFF3 12584960u    // Wk
#define OFF4 13633536u    // bk
#define OFF5 13634048u    // Wv
#define OFF6 14682624u    // bv
#define OFF7 14683136u    // Wo
#define OFF8 18877440u    // bo
#define NTOT 18879488u

__global__ __launch_bounds__(256) void convert_kernel(
    const void* p0, const void* p1, const void* p2, const void* p3, const void* p4,
    const void* p5, const void* p6, const void* p7, const void* p8,
    u16* __restrict__ C, const int* __restrict__ flagp)
{
    const int f = *flagp;
    unsigned int idx = blockIdx.x * 256u + threadIdx.x;
    if (idx >= NTOT) return;

    const void* src; unsigned int local;
    if      (idx < OFF1) { src = p0; local = idx; }
    else if (idx < OFF2) { src = p1; local = idx - OFF1; }
    else if (idx < OFF3) { src = p2; local = idx - OFF2; }
    else if (idx < OFF4) { src = p3; local = idx - OFF3; }
    else if (idx < OFF5) { src = p4; local = idx - OFF4; }
    else if (idx < OFF6) { src = p5; local = idx - OFF5; }
    else if (idx < OFF7) { src = p6; local = idx - OFF6; }
    else if (idx < OFF8) { src = p7; local = idx - OFF7; }
    else                 { src = p8; local = idx - OFF8; }

    u16 v = f ? f2bf(((const float*)src)[local]) : ((const u16*)src)[local];
    C[idx] = v;
}

// ---------------------------------------------------------------------------
// GEMM: C[m,n] = sum_k A[m,k] * W[n,k] + bias[n]; bf16 in, bf16 out.
// 64x64 tile, BK=32, 4 waves (2x2), each wave 32x32 via 2x2 MFMA 16x16x32.
// ---------------------------------------------------------------------------
#define BM 64
#define BN 64
#define BKK 32
#define LDK 40   // padded LDS row stride (u16); rows are 80B = 16B-aligned

__global__ __launch_bounds__(256) void gemm_bt_bias(
    const u16* __restrict__ A, const u16* __restrict__ W,
    const u16* __restrict__ bias, u16* __restrict__ C,
    int M, int N, int K)
{
    __shared__ __align__(16) u16 As[BM * LDK];
    __shared__ __align__(16) u16 Bs[BN * LDK];

    const int bn = blockIdx.x, bm = blockIdx.y;
    const int m0 = bm * BM, n0 = bn * BN;

    const int t = threadIdx.x;
    const int wave = t >> 6, lane = t & 63;
    const int waveM = wave >> 1, waveN = wave & 1;
    const int quad = lane >> 4, l16 = lane & 15;

    const int srow = t >> 2;          // 0..63
    const int scol = (t & 3) * 8;     // 0,8,16,24

    f32x4 acc[2][2];
    const f32x4 zero = {0.f, 0.f, 0.f, 0.f};
    acc[0][0] = zero; acc[0][1] = zero; acc[1][0] = zero; acc[1][1] = zero;

    for (int k0 = 0; k0 < K; k0 += BKK) {
        short8 av = *(const short8*)(A + (size_t)(m0 + srow) * K + k0 + scol);
        short8 bv = *(const short8*)(W + (size_t)(n0 + srow) * K + k0 + scol);
        __syncthreads();   // previous iteration's fragment reads complete
        *(short8*)(As + srow * LDK + scol) = av;
        *(short8*)(Bs + srow * LDK + scol) = bv;
        __syncthreads();

        #pragma unroll
        for (int mi = 0; mi < 2; ++mi) {
            // A-frag: lane holds A[m=l16][k=quad*8+j]
            short8 af = *(const short8*)(As + (waveM * 32 + mi * 16 + l16) * LDK + quad * 8);
            #pragma unroll
            for (int ni = 0; ni < 2; ++ni) {
                // B-frag: lane holds B[k=quad*8+j][n=l16] == W[n][k]
                short8 bf = *(const short8*)(Bs + (waveN * 32 + ni * 16 + l16) * LDK + quad * 8);
                acc[mi][ni] = __builtin_amdgcn_mfma_f32_16x16x32_bf16(af, bf, acc[mi][ni], 0, 0, 0);
            }
        }
    }

    // C/D layout: row = quad*4 + reg, col = l16
    #pragma unroll
    for (int mi = 0; mi < 2; ++mi) {
        #pragma unroll
        for (int ni = 0; ni < 2; ++ni) {
            int row0 = m0 + waveM * 32 + mi * 16 + quad * 4;
            int col  = n0 + waveN * 32 + ni * 16 + l16;
            float bb = bf2f(bias[col]);
            #pragma unroll
            for (int r = 0; r < 4; ++r) {
                C[(size_t)(row0 + r) * N + col] = f2bf(acc[mi][ni][r] + bb);
            }
        }
    }
}

// Same GEMM but the output dtype follows the runtime flag (final projection).
__global__ __launch_bounds__(256) void gemm_bt_bias_out(
    const u16* __restrict__ A, const u16* __restrict__ W,
    const u16* __restrict__ bias, void* __restrict__ Cout,
    int M, int N, int K, const int* __restrict__ flagp)
{
    __shared__ __align__(16) u16 As[BM * LDK];
    __shared__ __align__(16) u16 Bs[BN * LDK];

    const int bn = blockIdx.x, bm = blockIdx.y;
    const int m0 = bm * BM, n0 = bn * BN;

    const int t = threadIdx.x;
    const int wave = t >> 6, lane = t & 63;
    const int waveM = wave >> 1, waveN = wave & 1;
    const int quad = lane >> 4, l16 = lane & 15;

    const int srow = t >> 2;
    const int scol = (t & 3) * 8;

    f32x4 acc[2][2];
    const f32x4 zero = {0.f, 0.f, 0.f, 0.f};
    acc[0][0] = zero; acc[0][1] = zero; acc[1][0] = zero; acc[1][1] = zero;

    for (int k0 = 0; k0 < K; k0 += BKK) {
        short8 av = *(const short8*)(A + (size_t)(m0 + srow) * K + k0 + scol);
        short8 bv = *(const short8*)(W + (size_t)(n0 + srow) * K + k0 + scol);
        __syncthreads();
        *(short8*)(As + srow * LDK + scol) = av;
        *(short8*)(Bs + srow * LDK + scol) = bv;
        __syncthreads();

        #pragma unroll
        for (int mi = 0; mi < 2; ++mi) {
            short8 af = *(const short8*)(As + (waveM * 32 + mi * 16 + l16) * LDK + quad * 8);
            #pragma unroll
            for (int ni = 0; ni < 2; ++ni) {
                short8 bf = *(const short8*)(Bs + (waveN * 32 + ni * 16 + l16) * LDK + quad * 8);
                acc[mi][ni] = __builtin_amdgcn_mfma_f32_16x16x32_bf16(af, bf, acc[mi][ni], 0, 0, 0);
            }
        }
    }

    const int f = *flagp;
    #pragma unroll
    for (int mi = 0; mi < 2; ++mi) {
        #pragma unroll
        for (int ni = 0; ni < 2; ++ni) {
            int row0 = m0 + waveM * 32 + mi * 16 + quad * 4;
            int col  = n0 + waveN * 32 + ni * 16 + l16;
            float bb = bf2f(bias[col]);
            #pragma unroll
            for (int r = 0; r < 4; ++r) {
                float val = acc[mi][ni][r] + bb;
                size_t idx = (size_t)(row0 + r) * N + col;
                if (f) ((float*)Cout)[idx] = val;
                else   ((u16*)Cout)[idx]   = f2bf(val);
            }
        }
    }
}

// ---------------------------------------------------------------------------
// RoPE over Q (B,S,HQ,D) and K (B,S,HKV,D): pair (d, d+64), angle = s*invfreq.
// ---------------------------------------------------------------------------
__global__ __launch_bounds__(256) void rope_kernel(u16* __restrict__ Q, u16* __restrict__ Kb)
{
    const size_t qtot = (size_t)B_ * S_ * HQ_ * 64;
    const size_t ktot = (size_t)B_ * S_ * HKV_ * 64;
    size_t idx = (size_t)blockIdx.x * 256 + threadIdx.x;
    if (idx >= qtot + ktot) return;

    u16* base; int H; size_t r;
    if (idx < qtot) { base = Q; H = HQ_; r = idx; }
    else           { base = Kb; H = HKV_; r = idx - qtot; }

    int d = (int)(r & 63);
    size_t th = r >> 6;
    size_t tok = th / H;
    int s = (int)(tok & (S_ - 1));

    u16* p = base + th * (size_t)D_ + d;
    float x1 = bf2f(p[0]);
    float x2 = bf2f(p[64]);
    float inv_freq = __expf(-0.14391156514f * (float)d);   // 10000^(-d/64)
    float ang = (float)s * inv_freq;
    float sn, cs;
    sincosf(ang, &sn, &cs);
    p[0]  = f2bf(x1 * cs - x2 * sn);
    p[64] = f2bf(x1 * sn + x2 * cs);
}

// ---------------------------------------------------------------------------
// Flash attention, sliding window, GQA. One wave per query; 4 waves/block.
// ---------------------------------------------------------------------------
__global__ __launch_bounds__(256) void attn_kernel(
    const u16* __restrict__ Q, const u16* __restrict__ K,
    const u16* __restrict__ V, u16* __restrict__ O)
{
    __shared__ __align__(16) float qs[4][128];
    __shared__ float ps[4][64];

    const int t = threadIdx.x;
    const int w = t >> 6, lane = t & 63;

    const int i4 = blockIdx.x & (S_ / 4 - 1);
    const int bh = blockIdx.x >> 9;
    const int h = bh & (HQ_ - 1);
    const int b = bh >> 4;
    const int i = i4 * 4 + w;
    const int kh = h >> 2;

    const float scale = 0.08838834764831845f; // 1/sqrt(128)

    {
        const u16* qrow = Q + ((size_t)(b * S_ + i) * HQ_ + h) * D_;
        qs[w][lane]      = bf2f(qrow[lane]) * scale;
        qs[w][lane + 64] = bf2f(qrow[lane + 64]) * scale;
    }

    int jstart = i - WINDOW_; if (jstart < 0) jstart = 0;
    const int nj = i - jstart + 1;
    const int nchunk = (nj + 63) >> 6;

    float m = -1e30f, l = 0.0f, o0 = 0.0f, o1 = 0.0f;
    const f32x4* q4 = (const f32x4*)(qs[w]);

    for (int c = 0; c < nchunk; ++c) {
        const int jbase = jstart + c * 64;
        const int j = jbase + lane;
        float s = -1e30f;
        if (j <= i) {
            const u16* krow = K + ((size_t)(b * S_ + j) * HKV_ + kh) * D_;
            float a = 0.f;
            #pragma unroll
            for (int kk = 0; kk < 16; ++kk) {
                short8 kv = *(const short8*)(krow + kk * 8);
                f32x4 qa = q4[kk * 2];
                f32x4 qb = q4[kk * 2 + 1];
                a += qa[0] * bf2f((u16)kv[0]);
                a += qa[1] * bf2f((u16)kv[1]);
                a += qa[2] * bf2f((u16)kv[2]);
                a += qa[3] * bf2f((u16)kv[3]);
                a += qb[0] * bf2f((u16)kv[4]);
                a += qb[1] * bf2f((u16)kv[5]);
                a += qb[2] * bf2f((u16)kv[6]);
                a += qb[3] * bf2f((u16)kv[7]);
            }
            s = a;
        }
        float cmax = s;
        #pragma unroll
        for (int off = 32; off > 0; off >>= 1)
            cmax = fmaxf(cmax, __shfl_xor(cmax, off));
        float mnew = fmaxf(m, cmax);
        float p = __expf(s - mnew);
        float psum = p;
        #pragma unroll
        for (int off = 32; off > 0; off >>= 1)
            psum += __shfl_xor(psum, off);
        float alpha = __expf(m - mnew);
        l = l * alpha + psum;
        o0 *= alpha; o1 *= alpha;
        m = mnew;
        ps[w][lane] = p;

        int jmax = i < jbase + 63 ? i : jbase + 63;
        int cnt = jmax - jbase + 1;
        for (int jj = 0; jj < cnt; ++jj) {
            float pj = ps[w][jj];
            const u16* vrow = V + ((size_t)(b * S_ + jbase + jj) * HKV_ + kh) * D_;
            o0 += pj * bf2f(vrow[lane]);
            o1 += pj * bf2f(vrow[lane + 64]);
        }
    }

    float inv = 1.0f / l;
    u16* orow = O + ((size_t)(b * S_ + i) * HQ_ + h) * D_;
    orow[lane]      = f2bf(o0 * inv);
    orow[lane + 64] = f2bf(o1 * inv);
}

// ---------------------------------------------------------------------------
extern "C" void kernel_launch(void* const* d_in, const int* in_sizes, int n_in,
                              void* d_out, int out_size, void* d_ws, size_t ws_size,
                              hipStream_t stream)
{
    char* ws = (char*)d_ws;
    // canonical bf16 inputs (concatenated), then flag, then activations
    u16* C     = (u16*)ws;                               // 37,758,976 B
    int* flag  = (int*)(ws + 37758976);                  // 256 B slot
    u16* Qb    = (u16*)(ws + 37759232);                  // 16 MiB
    u16* Kb    = (u16*)(ws + 37759232 + 16777216);       //  4 MiB
    u16* Vb    = (u16*)(ws + 37759232 + 20971520);       //  4 MiB
    u16* Ab    = (u16*)(ws + 37759232 + 25165824);       // 16 MiB  (total ~76 MiB)

    const u16* xb  = C;
    const u16* Wqb = C + OFF1;
    const u16* bqb = C + OFF2;
    const u16* Wkb = C + OFF3;
    const u16* bkb = C + OFF4;
    const u16* Wvb = C + OFF5;
    const u16* bvb = C + OFF6;
    const u16* Wob = C + OFF7;
    const u16* bob = C + OFF8;

    const int M = B_ * S_;     // 4096
    dim3 blk(256);

    detect_kernel<<<1, blk, 0, stream>>>((const u16*)d_in[1], flag);

    convert_kernel<<<dim3((NTOT + 255) / 256), blk, 0, stream>>>(
        d_in[0], d_in[1], d_in[2], d_in[3], d_in[4], d_in[5], d_in[6], d_in[7], d_in[8],
        C, flag);

    gemm_bt_bias<<<dim3((HQ_ * D_) / BN, M / BM), blk, 0, stream>>>(xb, Wqb, bqb, Qb, M, HQ_ * D_, E_);
    gemm_bt_bias<<<dim3((HKV_ * D_) / BN, M / BM), blk, 0, stream>>>(xb, Wkb, bkb, Kb, M, HKV_ * D_, E_);
    gemm_bt_bias<<<dim3((HKV_ * D_) / BN, M / BM), blk, 0, stream>>>(xb, Wvb, bvb, Vb, M, HKV_ * D_, E_);

    size_t nrope = (size_t)M * (HQ_ + HKV_) * 64;
    rope_kernel<<<dim3((unsigned)((nrope + 255) / 256)), blk, 0, stream>>>(Qb, Kb);

    attn_kernel<<<dim3(B_ * HQ_ * (S_ / 4)), blk, 0, stream>>>(Qb, Kb, Vb, Ab);

    gemm_bt_bias_out<<<dim3(E_ / BN, M / BM), blk, 0, stream>>>(Ab, Wob, bob, d_out, M, E_, HQ_ * D_, flag);
}

// Round 3
// 477.055 us; speedup vs baseline: 3.4715x; 3.4715x over previous
//
#include <hip/hip_runtime.h>
#include <hip/hip_bf16.h>

typedef unsigned short u16;
typedef __attribute__((ext_vector_type(8))) short short8;
typedef __attribute__((ext_vector_type(4))) float f32x4;

#define B_ 2
#define S_ 2048
#define E_ 2048
#define HQ_ 16
#define HKV_ 4
#define D_ 128
#define WINDOW_ 512

static __device__ __forceinline__ float bf2f(u16 u) {
    union { unsigned int i; float f; } v; v.i = ((unsigned int)u) << 16; return v.f;
}
static __device__ __forceinline__ u16 f2bf(float f) {
    unsigned int x = __float_as_uint(f);
    unsigned int r = (x + 0x7fffu + ((x >> 16) & 1u)) >> 16;
    return (u16)r;
}

// ---------------------------------------------------------------------------
// Dtype detector: flag=1 -> inputs fp32, flag=0 -> bf16. (bf16 weights
// ~N(0,0.02) never have exponent >= 0x90; fp32 halfwords do ~45% of the time.)
// ---------------------------------------------------------------------------
__global__ void detect_kernel(const u16* __restrict__ Wq, int* __restrict__ flag)
{
    __shared__ int cnt;
    if (threadIdx.x == 0) cnt = 0;
    __syncthreads();
    int c = 0;
    #pragma unroll
    for (int k = 0; k < 16; ++k) {
        u16 v = Wq[threadIdx.x * 16 + k];
        int e = (v >> 7) & 0xFF;
        if (e >= 0x90) c++;
    }
    atomicAdd(&cnt, c);
    __syncthreads();
    if (threadIdx.x == 0) *flag = (cnt >= 256) ? 1 : 0;
}

// ---------------------------------------------------------------------------
// Converter: canonical bf16 copies of all inputs, concatenated in C.
// ---------------------------------------------------------------------------
#define NX   8388608u
#define OFF1 8388608u     // Wq
#define OFF2 12582912u    // bq
#define OFF3 12584960u    // Wk
#define OFF4 13633536u    // bk
#define OFF5 13634048u    // Wv
#define OFF6 14682624u    // bv
#define OFF7 14683136u    // Wo
#define OFF8 18877440u    // bo
#define NTOT 18879488u

__global__ __launch_bounds__(256) void convert_kernel(
    const void* p0, const void* p1, const void* p2, const void* p3, const void* p4,
    const void* p5, const void* p6, const void* p7, const void* p8,
    u16* __restrict__ C, const int* __restrict__ flagp)
{
    const int f = *flagp;
    unsigned int idx = blockIdx.x * 256u + threadIdx.x;
    if (idx >= NTOT) return;

    const void* src; unsigned int local;
    if      (idx < OFF1) { src = p0; local = idx; }
    else if (idx < OFF2) { src = p1; local = idx - OFF1; }
    else if (idx < OFF3) { src = p2; local = idx - OFF2; }
    else if (idx < OFF4) { src = p3; local = idx - OFF3; }
    else if (idx < OFF5) { src = p4; local = idx - OFF4; }
    else if (idx < OFF6) { src = p5; local = idx - OFF5; }
    else if (idx < OFF7) { src = p6; local = idx - OFF6; }
    else if (idx < OFF8) { src = p7; local = idx - OFF7; }
    else                 { src = p8; local = idx - OFF8; }

    u16 v = f ? f2bf(((const float*)src)[local]) : ((const u16*)src)[local];
    C[idx] = v;
}

// ---------------------------------------------------------------------------
// GEMM: C[m,n] = sum_k A[m,k] * W[n,k] + bias[n]; bf16 in, bf16 out.
// ---------------------------------------------------------------------------
#define BM 64
#define BN 64
#define BKK 32
#define LDK 40

__global__ __launch_bounds__(256) void gemm_bt_bias(
    const u16* __restrict__ A, const u16* __restrict__ W,
    const u16* __restrict__ bias, u16* __restrict__ C,
    int M, int N, int K)
{
    __shared__ __align__(16) u16 As[BM * LDK];
    __shared__ __align__(16) u16 Bs[BN * LDK];

    const int bn = blockIdx.x, bm = blockIdx.y;
    const int m0 = bm * BM, n0 = bn * BN;

    const int t = threadIdx.x;
    const int wave = t >> 6, lane = t & 63;
    const int waveM = wave >> 1, waveN = wave & 1;
    const int quad = lane >> 4, l16 = lane & 15;

    const int srow = t >> 2;
    const int scol = (t & 3) * 8;

    f32x4 acc[2][2];
    const f32x4 zero = {0.f, 0.f, 0.f, 0.f};
    acc[0][0] = zero; acc[0][1] = zero; acc[1][0] = zero; acc[1][1] = zero;

    for (int k0 = 0; k0 < K; k0 += BKK) {
        short8 av = *(const short8*)(A + (size_t)(m0 + srow) * K + k0 + scol);
        short8 bv = *(const short8*)(W + (size_t)(n0 + srow) * K + k0 + scol);
        __syncthreads();
        *(short8*)(As + srow * LDK + scol) = av;
        *(short8*)(Bs + srow * LDK + scol) = bv;
        __syncthreads();

        #pragma unroll
        for (int mi = 0; mi < 2; ++mi) {
            short8 af = *(const short8*)(As + (waveM * 32 + mi * 16 + l16) * LDK + quad * 8);
            #pragma unroll
            for (int ni = 0; ni < 2; ++ni) {
                short8 bf = *(const short8*)(Bs + (waveN * 32 + ni * 16 + l16) * LDK + quad * 8);
                acc[mi][ni] = __builtin_amdgcn_mfma_f32_16x16x32_bf16(af, bf, acc[mi][ni], 0, 0, 0);
            }
        }
    }

    #pragma unroll
    for (int mi = 0; mi < 2; ++mi) {
        #pragma unroll
        for (int ni = 0; ni < 2; ++ni) {
            int row0 = m0 + waveM * 32 + mi * 16 + quad * 4;
            int col  = n0 + waveN * 32 + ni * 16 + l16;
            float bb = bf2f(bias[col]);
            #pragma unroll
            for (int r = 0; r < 4; ++r) {
                C[(size_t)(row0 + r) * N + col] = f2bf(acc[mi][ni][r] + bb);
            }
        }
    }
}

// Same GEMM, output dtype follows the runtime flag (final projection).
__global__ __launch_bounds__(256) void gemm_bt_bias_out(
    const u16* __restrict__ A, const u16* __restrict__ W,
    const u16* __restrict__ bias, void* __restrict__ Cout,
    int M, int N, int K, const int* __restrict__ flagp)
{
    __shared__ __align__(16) u16 As[BM * LDK];
    __shared__ __align__(16) u16 Bs[BN * LDK];

    const int bn = blockIdx.x, bm = blockIdx.y;
    const int m0 = bm * BM, n0 = bn * BN;

    const int t = threadIdx.x;
    const int wave = t >> 6, lane = t & 63;
    const int waveM = wave >> 1, waveN = wave & 1;
    const int quad = lane >> 4, l16 = lane & 15;

    const int srow = t >> 2;
    const int scol = (t & 3) * 8;

    f32x4 acc[2][2];
    const f32x4 zero = {0.f, 0.f, 0.f, 0.f};
    acc[0][0] = zero; acc[0][1] = zero; acc[1][0] = zero; acc[1][1] = zero;

    for (int k0 = 0; k0 < K; k0 += BKK) {
        short8 av = *(const short8*)(A + (size_t)(m0 + srow) * K + k0 + scol);
        short8 bv = *(const short8*)(W + (size_t)(n0 + srow) * K + k0 + scol);
        __syncthreads();
        *(short8*)(As + srow * LDK + scol) = av;
        *(short8*)(Bs + srow * LDK + scol) = bv;
        __syncthreads();

        #pragma unroll
        for (int mi = 0; mi < 2; ++mi) {
            short8 af = *(const short8*)(As + (waveM * 32 + mi * 16 + l16) * LDK + quad * 8);
            #pragma unroll
            for (int ni = 0; ni < 2; ++ni) {
                short8 bf = *(const short8*)(Bs + (waveN * 32 + ni * 16 + l16) * LDK + quad * 8);
                acc[mi][ni] = __builtin_amdgcn_mfma_f32_16x16x32_bf16(af, bf, acc[mi][ni], 0, 0, 0);
            }
        }
    }

    const int f = *flagp;
    #pragma unroll
    for (int mi = 0; mi < 2; ++mi) {
        #pragma unroll
        for (int ni = 0; ni < 2; ++ni) {
            int row0 = m0 + waveM * 32 + mi * 16 + quad * 4;
            int col  = n0 + waveN * 32 + ni * 16 + l16;
            float bb = bf2f(bias[col]);
            #pragma unroll
            for (int r = 0; r < 4; ++r) {
                float val = acc[mi][ni][r] + bb;
                size_t idx = (size_t)(row0 + r) * N + col;
                if (f) ((float*)Cout)[idx] = val;
                else   ((u16*)Cout)[idx]   = f2bf(val);
            }
        }
    }
}

// ---------------------------------------------------------------------------
// RoPE over Q (B,S,HQ,D) and K (B,S,HKV,D): pair (d, d+64), angle = s*invfreq.
// ---------------------------------------------------------------------------
__global__ __launch_bounds__(256) void rope_kernel(u16* __restrict__ Q, u16* __restrict__ Kb)
{
    const size_t qtot = (size_t)B_ * S_ * HQ_ * 64;
    const size_t ktot = (size_t)B_ * S_ * HKV_ * 64;
    size_t idx = (size_t)blockIdx.x * 256 + threadIdx.x;
    if (idx >= qtot + ktot) return;

    u16* base; int H; size_t r;
    if (idx < qtot) { base = Q; H = HQ_; r = idx; }
    else           { base = Kb; H = HKV_; r = idx - qtot; }

    int d = (int)(r & 63);
    size_t th = r >> 6;
    size_t tok = th / H;
    int s = (int)(tok & (S_ - 1));

    u16* p = base + th * (size_t)D_ + d;
    float x1 = bf2f(p[0]);
    float x2 = bf2f(p[64]);
    float inv_freq = __expf(-0.14391156514f * (float)d);   // 10000^(-d/64)
    float ang = (float)s * inv_freq;
    float sn, cs;
    sincosf(ang, &sn, &cs);
    p[0]  = f2bf(x1 * cs - x2 * sn);
    p[64] = f2bf(x1 * sn + x2 * cs);
}

// ---------------------------------------------------------------------------
// MFMA flash attention, sliding window, GQA.
// Block: 64 queries of one (b, h); 4 waves x 16 queries.
// K/V staged in LDS per 32-key block (V transposed w/ xor-swizzled cols).
// QK^T and PV on 16x16x32 bf16 MFMA; P goes C-layout -> A-layout via LDS.
// ---------------------------------------------------------------------------
__global__ __launch_bounds__(256) void attn_mfma(
    const u16* __restrict__ Q, const u16* __restrict__ K,
    const u16* __restrict__ V, u16* __restrict__ O)
{
    __shared__ __align__(16) u16 Ks[32 * 136];   // [key][d], pad 128->136
    __shared__ __align__(16) u16 Vst[128 * 40];  // [d][key^swz], pad 32->40
    __shared__ __align__(16) u16 ps[4][16 * 40]; // per-wave P, [q][key], pad 32->40

    const int t = threadIdx.x;
    const int wv = t >> 6, lane = t & 63;
    const int quad = lane >> 4, l16 = lane & 15;

    const int tile = blockIdx.x & 31;            // S_/64 = 32
    const int h = (blockIdx.x >> 5) & 15;
    const int b = blockIdx.x >> 9;
    const int kh = h >> 2;

    const int i0b = tile * 64;
    const int i0w = i0b + wv * 16;
    const float scale = 0.08838834764831845f;    // 1/sqrt(128)

    // Q A-fragments in registers: lane holds Q[m=l16][k=quad*8+j], 4 K-chunks
    short8 qf[4];
    {
        const u16* qrow = Q + ((size_t)(b * S_ + i0w + l16) * HQ_ + h) * D_ + quad * 8;
        #pragma unroll
        for (int kc = 0; kc < 4; ++kc)
            qf[kc] = *(const short8*)(qrow + kc * 32);
    }

    f32x4 oc[8];
    #pragma unroll
    for (int c = 0; c < 8; ++c) oc[c] = (f32x4){0.f, 0.f, 0.f, 0.f};
    float m[4] = {-1e30f, -1e30f, -1e30f, -1e30f};
    float l[4] = {0.f, 0.f, 0.f, 0.f};

    int jlo = i0b - WINDOW_; if (jlo < 0) jlo = 0;
    const int nblk = (i0b + 64 - jlo) >> 5;      // exact multiples of 32

    for (int blk = 0; blk < nblk; ++blk) {
        const int jbase = jlo + blk * 32;
        __syncthreads();                          // prior iter frag reads done
        #pragma unroll
        for (int it = 0; it < 2; ++it) {
            int idx = it * 256 + t;               // 0..511
            int key = idx >> 4;                   // 0..31
            int c8  = (idx & 15) * 8;             // 0..120
            size_t grow = ((size_t)(b * S_ + jbase + key) * HKV_ + kh) * D_ + c8;
            short8 kvv = *(const short8*)(K + grow);
            *(short8*)(Ks + key * 136 + c8) = kvv;
            short8 vvv = *(const short8*)(V + grow);
            #pragma unroll
            for (int jj = 0; jj < 8; ++jj) {
                int d = c8 + jj;
                int col = key ^ (((d >> 3) & 3) << 3);   // bank-spread, keeps 8-contig
                Vst[d * 40 + col] = (u16)vvv[jj];
            }
        }
        __syncthreads();

        bool active = (jbase <= i0w + 15) && (jbase + 31 >= i0w - WINDOW_);
        if (!active) continue;                    // all waves still hit top barrier

        // QK^T: scores for 16 q x 32 keys (two C-frags)
        f32x4 sc0 = {0.f,0.f,0.f,0.f}, sc1 = {0.f,0.f,0.f,0.f};
        #pragma unroll
        for (int kc = 0; kc < 4; ++kc) {
            short8 kb0 = *(const short8*)(Ks + l16 * 136 + kc * 32 + quad * 8);
            short8 kb1 = *(const short8*)(Ks + (16 + l16) * 136 + kc * 32 + quad * 8);
            sc0 = __builtin_amdgcn_mfma_f32_16x16x32_bf16(qf[kc], kb0, sc0, 0, 0, 0);
            sc1 = __builtin_amdgcn_mfma_f32_16x16x32_bf16(qf[kc], kb1, sc1, 0, 0, 0);
        }

        // online softmax in raw units; scale folded into exp args
        const int j0 = jbase + l16, j1 = j0 + 16;
        const int iq = i0w + quad * 4;
        float p0[4], p1[4], alpha[4];
        #pragma unroll
        for (int r = 0; r < 4; ++r) {
            int i = iq + r;
            bool ok0 = (unsigned)(i - j0) <= (unsigned)WINDOW_;
            bool ok1 = (unsigned)(i - j1) <= (unsigned)WINDOW_;
            float s0 = ok0 ? sc0[r] : -1e30f;
            float s1 = ok1 ? sc1[r] : -1e30f;
            float mx = fmaxf(s0, s1);
            mx = fmaxf(mx, __shfl_xor(mx, 1));
            mx = fmaxf(mx, __shfl_xor(mx, 2));
            mx = fmaxf(mx, __shfl_xor(mx, 4));
            mx = fmaxf(mx, __shfl_xor(mx, 8));
            float mnew = fmaxf(m[r], mx);
            alpha[r] = __expf((m[r] - mnew) * scale);
            p0[r] = ok0 ? __expf((sc0[r] - mnew) * scale) : 0.f;  // explicit 0 (all-masked trap)
            p1[r] = ok1 ? __expf((sc1[r] - mnew) * scale) : 0.f;
            float rs = p0[r] + p1[r];
            rs += __shfl_xor(rs, 1);
            rs += __shfl_xor(rs, 2);
            rs += __shfl_xor(rs, 4);
            rs += __shfl_xor(rs, 8);
            l[r] = l[r] * alpha[r] + rs;
            m[r] = mnew;
        }
        #pragma unroll
        for (int c = 0; c < 8; ++c)
            #pragma unroll
            for (int r = 0; r < 4; ++r)
                oc[c][r] *= alpha[r];

        // P: C-layout -> A-layout via per-wave LDS (intra-wave, no barrier)
        u16* pw = ps[wv];
        #pragma unroll
        for (int r = 0; r < 4; ++r) {
            pw[(quad * 4 + r) * 40 + l16]      = f2bf(p0[r]);
            pw[(quad * 4 + r) * 40 + 16 + l16] = f2bf(p1[r]);
        }
        short8 pa = *(const short8*)(pw + l16 * 40 + quad * 8);

        // PV: O += P(16x32) @ V(32x128), 8 d-chunks
        #pragma unroll
        for (int c = 0; c < 8; ++c) {
            int row = c * 16 + l16;
            int colstart = (quad * 8) ^ (((row >> 3) & 3) << 3);
            short8 vb = *(const short8*)(Vst + row * 40 + colstart);
            oc[c] = __builtin_amdgcn_mfma_f32_16x16x32_bf16(pa, vb, oc[c], 0, 0, 0);
        }
    }

    float inv0[4];
    #pragma unroll
    for (int r = 0; r < 4; ++r) inv0[r] = 1.0f / l[r];
    #pragma unroll
    for (int c = 0; c < 8; ++c) {
        #pragma unroll
        for (int r = 0; r < 4; ++r) {
            O[((size_t)(b * S_ + i0w + quad * 4 + r) * HQ_ + h) * D_ + c * 16 + l16] =
                f2bf(oc[c][r] * inv0[r]);
        }
    }
}

// ---------------------------------------------------------------------------
extern "C" void kernel_launch(void* const* d_in, const int* in_sizes, int n_in,
                              void* d_out, int out_size, void* d_ws, size_t ws_size,
                              hipStream_t stream)
{
    char* ws = (char*)d_ws;
    u16* C     = (u16*)ws;                               // 37,758,976 B
    int* flag  = (int*)(ws + 37758976);                  // 256 B slot
    u16* Qb    = (u16*)(ws + 37759232);                  // 16 MiB
    u16* Kb    = (u16*)(ws + 37759232 + 16777216);       //  4 MiB
    u16* Vb    = (u16*)(ws + 37759232 + 20971520);       //  4 MiB
    u16* Ab    = (u16*)(ws + 37759232 + 25165824);       // 16 MiB

    const u16* xb  = C;
    const u16* Wqb = C + OFF1;
    const u16* bqb = C + OFF2;
    const u16* Wkb = C + OFF3;
    const u16* bkb = C + OFF4;
    const u16* Wvb = C + OFF5;
    const u16* bvb = C + OFF6;
    const u16* Wob = C + OFF7;
    const u16* bob = C + OFF8;

    const int M = B_ * S_;     // 4096
    dim3 blk(256);

    detect_kernel<<<1, blk, 0, stream>>>((const u16*)d_in[1], flag);

    convert_kernel<<<dim3((NTOT + 255) / 256), blk, 0, stream>>>(
        d_in[0], d_in[1], d_in[2], d_in[3], d_in[4], d_in[5], d_in[6], d_in[7], d_in[8],
        C, flag);

    gemm_bt_bias<<<dim3((HQ_ * D_) / BN, M / BM), blk, 0, stream>>>(xb, Wqb, bqb, Qb, M, HQ_ * D_, E_);
    gemm_bt_bias<<<dim3((HKV_ * D_) / BN, M / BM), blk, 0, stream>>>(xb, Wkb, bkb, Kb, M, HKV_ * D_, E_);
    gemm_bt_bias<<<dim3((HKV_ * D_) / BN, M / BM), blk, 0, stream>>>(xb, Wvb, bvb, Vb, M, HKV_ * D_, E_);

    size_t nrope = (size_t)M * (HQ_ + HKV_) * 64;
    rope_kernel<<<dim3((unsigned)((nrope + 255) / 256)), blk, 0, stream>>>(Qb, Kb);

    attn_mfma<<<dim3(B_ * HQ_ * (S_ / 64)), blk, 0, stream>>>(Qb, Kb, Vb, Ab);

    gemm_bt_bias_out<<<dim3(E_ / BN, M / BM), blk, 0, stream>>>(Ab, Wob, bob, d_out, M, E_, HQ_ * D_, flag);
}

// Round 4
// 353.813 us; speedup vs baseline: 4.6807x; 1.3483x over previous
//
#include <hip/hip_runtime.h>
#include <hip/hip_bf16.h>

typedef unsigned short u16;
typedef __attribute__((ext_vector_type(8))) short short8;
typedef __attribute__((ext_vector_type(4))) float f32x4;

#define B_ 2
#define S_ 2048
#define E_ 2048
#define HQ_ 16
#define HKV_ 4
#define D_ 128
#define WINDOW_ 512

static __device__ __forceinline__ float bf2f(u16 u) {
    union { unsigned int i; float f; } v; v.i = ((unsigned int)u) << 16; return v.f;
}
static __device__ __forceinline__ u16 f2bf(float f) {
    unsigned int x = __float_as_uint(f);
    unsigned int r = (x + 0x7fffu + ((x >> 16) & 1u)) >> 16;
    return (u16)r;
}

// async global->LDS, 16B per lane; LDS dest = wave-uniform base + lane*16
static __device__ __forceinline__ void gload_lds16(const u16* g, u16* l) {
    __builtin_amdgcn_global_load_lds(
        (const __attribute__((address_space(1))) unsigned int*)g,
        (__attribute__((address_space(3))) unsigned int*)l,
        16, 0, 0);
}

// ---------------------------------------------------------------------------
// Dtype detector: flag=1 -> inputs fp32, flag=0 -> bf16.
// ---------------------------------------------------------------------------
__global__ void detect_kernel(const u16* __restrict__ Wq, int* __restrict__ flag)
{
    __shared__ int cnt;
    if (threadIdx.x == 0) cnt = 0;
    __syncthreads();
    int c = 0;
    #pragma unroll
    for (int k = 0; k < 16; ++k) {
        u16 v = Wq[threadIdx.x * 16 + k];
        int e = (v >> 7) & 0xFF;
        if (e >= 0x90) c++;
    }
    atomicAdd(&cnt, c);
    __syncthreads();
    if (threadIdx.x == 0) *flag = (cnt >= 256) ? 1 : 0;
}

// ---------------------------------------------------------------------------
// Converter: canonical bf16 inputs, packed as x | Wq|Wk|Wv | bq|bk|bv | Wo | bo
// so QKV projection is a single GEMM with W (3072 x 2048) and bias (3072).
// ---------------------------------------------------------------------------
#define C_WQ   8388608u
#define C_WK   12582912u
#define C_WV   13631488u
#define C_BQ   14680064u
#define C_BK   14682112u
#define C_BV   14682624u
#define C_WO   14683136u
#define C_BO   18877440u
#define NTOT   18879488u

__global__ __launch_bounds__(256) void convert_kernel(
    const void* p0, const void* p1, const void* p2, const void* p3, const void* p4,
    const void* p5, const void* p6, const void* p7, const void* p8,
    u16* __restrict__ C, const int* __restrict__ flagp)
{
    const int f = *flagp;
    unsigned int idx = blockIdx.x * 256u + threadIdx.x;
    if (idx >= NTOT) return;

    const void* src; unsigned int local;
    if      (idx < C_WQ) { src = p0; local = idx; }          // x
    else if (idx < C_WK) { src = p1; local = idx - C_WQ; }   // Wq
    else if (idx < C_WV) { src = p3; local = idx - C_WK; }   // Wk
    else if (idx < C_BQ) { src = p5; local = idx - C_WV; }   // Wv
    else if (idx < C_BK) { src = p2; local = idx - C_BQ; }   // bq
    else if (idx < C_BV) { src = p4; local = idx - C_BK; }   // bk
    else if (idx < C_WO) { src = p6; local = idx - C_BV; }   // bv
    else if (idx < C_BO) { src = p7; local = idx - C_WO; }   // Wo
    else                 { src = p8; local = idx - C_BO; }   // bo

    u16 v = f ? f2bf(((const float*)src)[local]) : ((const u16*)src)[local];
    C[idx] = v;
}

// ---------------------------------------------------------------------------
// 128x128-tile GEMM (m97 structure): C[m,n] = sum_k A[m,k]*W[n,k] + bias[n].
// 4 waves (2x2), each 64x64 via 4x4 MFMA 16x16x32; global_load_lds width=16.
// LDS tiles are contiguous [row][32] (required by global_load_lds lane order).
// ---------------------------------------------------------------------------
#define TBK 32

__global__ __launch_bounds__(256) void gemm128(
    const u16* __restrict__ A, const u16* __restrict__ W,
    const u16* __restrict__ bias, u16* __restrict__ C,
    int M, int N, int K)
{
    __shared__ __align__(16) u16 As[128 * TBK];
    __shared__ __align__(16) u16 Bs[128 * TBK];

    const int m0 = blockIdx.y * 128, n0 = blockIdx.x * 128;

    const int t = threadIdx.x;
    const int wv = t >> 6, lane = t & 63;
    const int waveM = wv >> 1, waveN = wv & 1;
    const int quad = lane >> 4, l16 = lane & 15;

    const int lrow = lane >> 2;        // 0..15
    const int lcol = (lane & 3) * 8;   // 0,8,16,24

    f32x4 acc[4][4];
    #pragma unroll
    for (int mi = 0; mi < 4; ++mi)
        #pragma unroll
        for (int ni = 0; ni < 4; ++ni)
            acc[mi][ni] = (f32x4){0.f, 0.f, 0.f, 0.f};

    const u16* ga = A + (size_t)(m0 + wv * 32 + lrow) * K + lcol;
    const u16* gb = W + (size_t)(n0 + wv * 32 + lrow) * K + lcol;
    u16* la0 = As + (wv * 32) * TBK;
    u16* la1 = As + (wv * 32 + 16) * TBK;
    u16* lb0 = Bs + (wv * 32) * TBK;
    u16* lb1 = Bs + (wv * 32 + 16) * TBK;

    for (int k0 = 0; k0 < K; k0 += TBK) {
        __syncthreads();                       // prev iter frag reads complete
        gload_lds16(ga + k0, la0);
        gload_lds16(ga + k0 + (size_t)16 * K, la1);
        gload_lds16(gb + k0, lb0);
        gload_lds16(gb + k0 + (size_t)16 * K, lb1);
        __syncthreads();                       // drains vmcnt -> LDS valid

        short8 af[4];
        #pragma unroll
        for (int mi = 0; mi < 4; ++mi)
            af[mi] = *(const short8*)(As + (waveM * 64 + mi * 16 + l16) * TBK + quad * 8);
        #pragma unroll
        for (int ni = 0; ni < 4; ++ni) {
            short8 bf = *(const short8*)(Bs + (waveN * 64 + ni * 16 + l16) * TBK + quad * 8);
            #pragma unroll
            for (int mi = 0; mi < 4; ++mi)
                acc[mi][ni] = __builtin_amdgcn_mfma_f32_16x16x32_bf16(af[mi], bf, acc[mi][ni], 0, 0, 0);
        }
    }

    // C/D layout: row = quad*4 + r, col = l16
    #pragma unroll
    for (int mi = 0; mi < 4; ++mi) {
        #pragma unroll
        for (int ni = 0; ni < 4; ++ni) {
            int row0 = m0 + waveM * 64 + mi * 16 + quad * 4;
            int col  = n0 + waveN * 64 + ni * 16 + l16;
            float bb = bf2f(bias[col]);
            #pragma unroll
            for (int r = 0; r < 4; ++r)
                C[(size_t)(row0 + r) * N + col] = f2bf(acc[mi][ni][r] + bb);
        }
    }
}

// Same, output dtype follows the runtime flag (final projection).
__global__ __launch_bounds__(256) void gemm128_out(
    const u16* __restrict__ A, const u16* __restrict__ W,
    const u16* __restrict__ bias, void* __restrict__ Cout,
    int M, int N, int K, const int* __restrict__ flagp)
{
    __shared__ __align__(16) u16 As[128 * TBK];
    __shared__ __align__(16) u16 Bs[128 * TBK];

    const int m0 = blockIdx.y * 128, n0 = blockIdx.x * 128;

    const int t = threadIdx.x;
    const int wv = t >> 6, lane = t & 63;
    const int waveM = wv >> 1, waveN = wv & 1;
    const int quad = lane >> 4, l16 = lane & 15;

    const int lrow = lane >> 2;
    const int lcol = (lane & 3) * 8;

    f32x4 acc[4][4];
    #pragma unroll
    for (int mi = 0; mi < 4; ++mi)
        #pragma unroll
        for (int ni = 0; ni < 4; ++ni)
            acc[mi][ni] = (f32x4){0.f, 0.f, 0.f, 0.f};

    const u16* ga = A + (size_t)(m0 + wv * 32 + lrow) * K + lcol;
    const u16* gb = W + (size_t)(n0 + wv * 32 + lrow) * K + lcol;
    u16* la0 = As + (wv * 32) * TBK;
    u16* la1 = As + (wv * 32 + 16) * TBK;
    u16* lb0 = Bs + (wv * 32) * TBK;
    u16* lb1 = Bs + (wv * 32 + 16) * TBK;

    for (int k0 = 0; k0 < K; k0 += TBK) {
        __syncthreads();
        gload_lds16(ga + k0, la0);
        gload_lds16(ga + k0 + (size_t)16 * K, la1);
        gload_lds16(gb + k0, lb0);
        gload_lds16(gb + k0 + (size_t)16 * K, lb1);
        __syncthreads();

        short8 af[4];
        #pragma unroll
        for (int mi = 0; mi < 4; ++mi)
            af[mi] = *(const short8*)(As + (waveM * 64 + mi * 16 + l16) * TBK + quad * 8);
        #pragma unroll
        for (int ni = 0; ni < 4; ++ni) {
            short8 bf = *(const short8*)(Bs + (waveN * 64 + ni * 16 + l16) * TBK + quad * 8);
            #pragma unroll
            for (int mi = 0; mi < 4; ++mi)
                acc[mi][ni] = __builtin_amdgcn_mfma_f32_16x16x32_bf16(af[mi], bf, acc[mi][ni], 0, 0, 0);
        }
    }

    const int f = *flagp;
    #pragma unroll
    for (int mi = 0; mi < 4; ++mi) {
        #pragma unroll
        for (int ni = 0; ni < 4; ++ni) {
            int row0 = m0 + waveM * 64 + mi * 16 + quad * 4;
            int col  = n0 + waveN * 64 + ni * 16 + l16;
            float bb = bf2f(bias[col]);
            #pragma unroll
            for (int r = 0; r < 4; ++r) {
                float val = acc[mi][ni][r] + bb;
                size_t idx = (size_t)(row0 + r) * N + col;
                if (f) ((float*)Cout)[idx] = val;
                else   ((u16*)Cout)[idx]   = f2bf(val);
            }
        }
    }
}

// ---------------------------------------------------------------------------
// RoPE over packed QKV (token stride 3072): Q at col 0 (16 heads), K at 2048.
// ---------------------------------------------------------------------------
__global__ __launch_bounds__(256) void rope_kernel(u16* __restrict__ QKV)
{
    const size_t qtot = (size_t)B_ * S_ * HQ_ * 64;   // 4,194,304
    const size_t ktot = (size_t)B_ * S_ * HKV_ * 64;  // 1,048,576
    size_t idx = (size_t)blockIdx.x * 256 + threadIdx.x;
    if (idx >= qtot + ktot) return;

    int d; size_t tok; u16* p;
    if (idx < qtot) {
        d = (int)(idx & 63);
        size_t th = idx >> 6;
        int h = (int)(th & 15);
        tok = th >> 4;
        p = QKV + tok * 3072 + h * 128 + d;
    } else {
        size_t r = idx - qtot;
        d = (int)(r & 63);
        size_t th = r >> 6;
        int kh = (int)(th & 3);
        tok = th >> 2;
        p = QKV + tok * 3072 + 2048 + kh * 128 + d;
    }
    int s = (int)(tok & (S_ - 1));

    float x1 = bf2f(p[0]);
    float x2 = bf2f(p[64]);
    float inv_freq = __expf(-0.14391156514f * (float)d);   // 10000^(-d/64)
    float ang = (float)s * inv_freq;
    float sn, cs;
    sincosf(ang, &sn, &cs);
    p[0]  = f2bf(x1 * cs - x2 * sn);
    p[64] = f2bf(x1 * sn + x2 * cs);
}

// ---------------------------------------------------------------------------
// MFMA flash attention over packed QKV, sliding window, GQA.
// Block: 64 queries of one (b, h); 4 waves x 16 queries.
// ---------------------------------------------------------------------------
__global__ __launch_bounds__(256) void attn_mfma(
    const u16* __restrict__ QKV, u16* __restrict__ O)
{
    __shared__ __align__(16) u16 Ks[32 * 136];   // [key][d], pad 128->136
    __shared__ __align__(16) u16 Vst[128 * 40];  // [d][key^swz], pad 32->40
    __shared__ __align__(16) u16 ps[4][16 * 40]; // per-wave P, [q][key]

    const int t = threadIdx.x;
    const int wv = t >> 6, lane = t & 63;
    const int quad = lane >> 4, l16 = lane & 15;

    const int tile = blockIdx.x & 31;            // S_/64 = 32
    const int h = (blockIdx.x >> 5) & 15;
    const int b = blockIdx.x >> 9;
    const int kh = h >> 2;

    const int i0b = tile * 64;
    const int i0w = i0b + wv * 16;
    const float scale = 0.08838834764831845f;    // 1/sqrt(128)

    short8 qf[4];
    {
        const u16* qrow = QKV + (size_t)(b * S_ + i0w + l16) * 3072 + h * 128 + quad * 8;
        #pragma unroll
        for (int kc = 0; kc < 4; ++kc)
            qf[kc] = *(const short8*)(qrow + kc * 32);
    }

    f32x4 oc[8];
    #pragma unroll
    for (int c = 0; c < 8; ++c) oc[c] = (f32x4){0.f, 0.f, 0.f, 0.f};
    float m[4] = {-1e30f, -1e30f, -1e30f, -1e30f};
    float l[4] = {0.f, 0.f, 0.f, 0.f};

    int jlo = i0b - WINDOW_; if (jlo < 0) jlo = 0;
    const int nblk = (i0b + 64 - jlo) >> 5;

    for (int blk = 0; blk < nblk; ++blk) {
        const int jbase = jlo + blk * 32;
        __syncthreads();
        #pragma unroll
        for (int it = 0; it < 2; ++it) {
            int idx = it * 256 + t;               // 0..511
            int key = idx >> 4;                   // 0..31
            int c8  = (idx & 15) * 8;             // 0..120
            size_t grow = (size_t)(b * S_ + jbase + key) * 3072 + 2048 + kh * 128 + c8;
            short8 kvv = *(const short8*)(QKV + grow);
            *(short8*)(Ks + key * 136 + c8) = kvv;
            short8 vvv = *(const short8*)(QKV + grow + 512);
            #pragma unroll
            for (int jj = 0; jj < 8; ++jj) {
                int d = c8 + jj;
                int col = key ^ (((d >> 3) & 3) << 3);
                Vst[d * 40 + col] = (u16)vvv[jj];
            }
        }
        __syncthreads();

        bool active = (jbase <= i0w + 15) && (jbase + 31 >= i0w - WINDOW_);
        if (!active) continue;

        f32x4 sc0 = {0.f,0.f,0.f,0.f}, sc1 = {0.f,0.f,0.f,0.f};
        #pragma unroll
        for (int kc = 0; kc < 4; ++kc) {
            short8 kb0 = *(const short8*)(Ks + l16 * 136 + kc * 32 + quad * 8);
            short8 kb1 = *(const short8*)(Ks + (16 + l16) * 136 + kc * 32 + quad * 8);
            sc0 = __builtin_amdgcn_mfma_f32_16x16x32_bf16(qf[kc], kb0, sc0, 0, 0, 0);
            sc1 = __builtin_amdgcn_mfma_f32_16x16x32_bf16(qf[kc], kb1, sc1, 0, 0, 0);
        }

        const int j0 = jbase + l16, j1 = j0 + 16;
        const int iq = i0w + quad * 4;
        float p0[4], p1[4], alpha[4];
        #pragma unroll
        for (int r = 0; r < 4; ++r) {
            int i = iq + r;
            bool ok0 = (unsigned)(i - j0) <= (unsigned)WINDOW_;
            bool ok1 = (unsigned)(i - j1) <= (unsigned)WINDOW_;
            float s0 = ok0 ? sc0[r] : -1e30f;
            float s1 = ok1 ? sc1[r] : -1e30f;
            float mx = fmaxf(s0, s1);
            mx = fmaxf(mx, __shfl_xor(mx, 1));
            mx = fmaxf(mx, __shfl_xor(mx, 2));
            mx = fmaxf(mx, __shfl_xor(mx, 4));
            mx = fmaxf(mx, __shfl_xor(mx, 8));
            float mnew = fmaxf(m[r], mx);
            alpha[r] = __expf((m[r] - mnew) * scale);
            p0[r] = ok0 ? __expf((sc0[r] - mnew) * scale) : 0.f;
            p1[r] = ok1 ? __expf((sc1[r] - mnew) * scale) : 0.f;
            float rs = p0[r] + p1[r];
            rs += __shfl_xor(rs, 1);
            rs += __shfl_xor(rs, 2);
            rs += __shfl_xor(rs, 4);
            rs += __shfl_xor(rs, 8);
            l[r] = l[r] * alpha[r] + rs;
            m[r] = mnew;
        }
        #pragma unroll
        for (int c = 0; c < 8; ++c)
            #pragma unroll
            for (int r = 0; r < 4; ++r)
                oc[c][r] *= alpha[r];

        u16* pw = ps[wv];
        #pragma unroll
        for (int r = 0; r < 4; ++r) {
            pw[(quad * 4 + r) * 40 + l16]      = f2bf(p0[r]);
            pw[(quad * 4 + r) * 40 + 16 + l16] = f2bf(p1[r]);
        }
        short8 pa = *(const short8*)(pw + l16 * 40 + quad * 8);

        #pragma unroll
        for (int c = 0; c < 8; ++c) {
            int row = c * 16 + l16;
            int colstart = (quad * 8) ^ (((row >> 3) & 3) << 3);
            short8 vb = *(const short8*)(Vst + row * 40 + colstart);
            oc[c] = __builtin_amdgcn_mfma_f32_16x16x32_bf16(pa, vb, oc[c], 0, 0, 0);
        }
    }

    float inv0[4];
    #pragma unroll
    for (int r = 0; r < 4; ++r) inv0[r] = 1.0f / l[r];
    #pragma unroll
    for (int c = 0; c < 8; ++c) {
        #pragma unroll
        for (int r = 0; r < 4; ++r) {
            O[((size_t)(b * S_ + i0w + quad * 4 + r) * HQ_ + h) * D_ + c * 16 + l16] =
                f2bf(oc[c][r] * inv0[r]);
        }
    }
}

// ---------------------------------------------------------------------------
extern "C" void kernel_launch(void* const* d_in, const int* in_sizes, int n_in,
                              void* d_out, int out_size, void* d_ws, size_t ws_size,
                              hipStream_t stream)
{
    char* ws = (char*)d_ws;
    u16* Cc   = (u16*)ws;                                 // 37,758,976 B
    int* flag = (int*)(ws + 37758976);                    // 256 B
    u16* QKV  = (u16*)(ws + 37759232);                    // 4096*3072*2 = 25,165,824 B
    u16* Ab   = (u16*)(ws + 37759232 + 25165824);         // 16,777,216 B

    const u16* xb    = Cc;
    const u16* Wqkv  = Cc + C_WQ;
    const u16* bqkv  = Cc + C_BQ;
    const u16* Wob   = Cc + C_WO;
    const u16* bob   = Cc + C_BO;

    const int M = B_ * S_;     // 4096
    dim3 blk(256);

    detect_kernel<<<1, blk, 0, stream>>>((const u16*)d_in[1], flag);

    convert_kernel<<<dim3((NTOT + 255) / 256), blk, 0, stream>>>(
        d_in[0], d_in[1], d_in[2], d_in[3], d_in[4], d_in[5], d_in[6], d_in[7], d_in[8],
        Cc, flag);

    // fused QKV projection: (4096 x 2048) @ (3072 x 2048)^T
    gemm128<<<dim3(3072 / 128, M / 128), blk, 0, stream>>>(xb, Wqkv, bqkv, QKV, M, 3072, E_);

    size_t nrope = (size_t)M * (HQ_ + HKV_) * 64;
    rope_kernel<<<dim3((unsigned)((nrope + 255) / 256)), blk, 0, stream>>>(QKV);

    attn_mfma<<<dim3(B_ * HQ_ * (S_ / 64)), blk, 0, stream>>>(QKV, Ab);

    gemm128_out<<<dim3(E_ / 128, M / 128), blk, 0, stream>>>(Ab, Wob, bob, d_out, M, E_, HQ_ * D_, flag);
}